// Round 3
// baseline (1099.373 us; speedup 1.0000x reference)
//
#include <hip/hip_runtime.h>
#include <hip/hip_bf16.h>

#define N_NODES 50000
#define N_EDGES 1600000
#define IN_H 256
#define NHEAD 4
#define EDGE_H 64
#define N_ET 8

// ---- ws layout (float/int word offsets), total 5,350,112 words = 21.4 MB ----
// counts  int[50000]   @ 0          (zeroed)
// cursor  int[50000]   @ 50000      (zeroed)
// gmax    uint[1]      @ 100000     (zeroed)
// flag    int[1]       @ 100001     (written by k_detect)
// offsets int[50001]   @ 100064     (pad to 150080)
// hl      f32[200000]  @ 150080
// hr      f32[200000]  @ 350080
// he      f32[32]      @ 550080
// perm    int[1600000] @ 550112
// h       bf16[6400000]@ 2150112    (3200000 words)

__device__ __forceinline__ float ldT(const float* p) { return *p; }
__device__ __forceinline__ float ldT(const __hip_bfloat16* p) { return __bfloat162float(*p); }
__device__ __forceinline__ void stT(float* p, float v) { *p = v; }
__device__ __forceinline__ void stT(__hip_bfloat16* p, float v) { *p = __float2bfloat16(v); }

__device__ __forceinline__ unsigned enc_f32(float f) {
    unsigned u = __float_as_uint(f);
    return (u & 0x80000000u) ? ~u : (u | 0x80000000u);
}
__device__ __forceinline__ float dec_f32(unsigned u) {
    return __uint_as_float((u & 0x80000000u) ? (u & 0x7fffffffu) : ~u);
}
__device__ __forceinline__ float lrelu(float v) { return v > 0.f ? v : 0.2f * v; }

// dtype detector: fp32 N(0,1) words have exp-field in [64,160]; bf16-packed don't.
__global__ void k_detect(const unsigned* __restrict__ xw, int* __restrict__ flag) {
    int lane = threadIdx.x;   // 64 threads
    int cnt = 0;
    for (int i = lane; i < 1024; i += 64) {
        unsigned e = (xw[i] >> 23) & 255u;
        if (e >= 64u && e <= 160u) cnt++;
    }
    for (int off = 32; off; off >>= 1) cnt += __shfl_xor(cnt, off);
    if (lane == 0) *flag = (cnt > 512) ? 1 : 0;   // 1 = fp32, 0 = bf16
}

// h = x @ W, scalar; one wave per node, lane covers cols {lane, lane+64}
template<typename T, int EXPECT>
__global__ __launch_bounds__(256) void k_node_proj_s(
    const void* __restrict__ xv, const void* __restrict__ Wv,
    __hip_bfloat16* __restrict__ h, const int* __restrict__ flag) {
    if (*flag != EXPECT) return;
    const T* x = (const T*)xv;
    const T* W = (const T*)Wv;
    int node = (blockIdx.x << 2) + (threadIdx.x >> 6);
    if (node >= N_NODES) return;
    int lane = threadIdx.x & 63;
    float acc0 = 0.f, acc1 = 0.f;
    const T* xrow = x + (size_t)node * IN_H;
    for (int k = 0; k < IN_H; ++k) {
        float xk = ldT(xrow + k);
        acc0 += xk * ldT(W + k * 128 + lane);
        acc1 += xk * ldT(W + k * 128 + 64 + lane);
    }
    if (acc0 != acc0) acc0 = 0.f;
    if (acc1 != acc1) acc1 = 0.f;
    h[(size_t)node * 128 + lane]      = __float2bfloat16(acc0);
    h[(size_t)node * 128 + 64 + lane] = __float2bfloat16(acc1);
}

// h_e[ty][head] = sum_d ae[head][d] * (emb[ty] @ We)[head*64+d]
template<typename T, int EXPECT>
__global__ __launch_bounds__(256) void k_edge_proj(
    const void* __restrict__ embv, const void* __restrict__ Wev,
    const void* __restrict__ aev, float* __restrict__ h_e,
    const int* __restrict__ flag) {
    if (*flag != EXPECT) return;
    const T* emb = (const T*)embv;
    const T* We  = (const T*)Wev;
    const T* ae  = (const T*)aev;
    int t = threadIdx.x;          // col 0..255, head = t>>6
    int lane = t & 63;
    float aev_ = ldT(ae + t);
    for (int ty = 0; ty < N_ET; ++ty) {
        float acc = 0.f;
        for (int k = 0; k < EDGE_H; ++k)
            acc += ldT(emb + ty * EDGE_H + k) * ldT(We + k * 256 + t);
        float v = aev_ * acc;
        for (int off = 32; off; off >>= 1) v += __shfl_xor(v, off);
        if (lane == 0) h_e[ty * NHEAD + (t >> 6)] = v;
    }
}

// hl/hr: one wave per node; lane holds flat dims {2*lane, 2*lane+1}
template<typename T, int EXPECT>
__global__ __launch_bounds__(256) void k_hlr(
    const __hip_bfloat16* __restrict__ h,
    const void* __restrict__ alv, const void* __restrict__ arv,
    float* __restrict__ hl, float* __restrict__ hr,
    const int* __restrict__ flag) {
    if (*flag != EXPECT) return;
    const T* al = (const T*)alv;
    const T* ar = (const T*)arv;
    int node = (blockIdx.x << 2) + (threadIdx.x >> 6);
    if (node >= N_NODES) return;
    int lane = threadIdx.x & 63;
    const __hip_bfloat16* hp = h + (size_t)node * 128 + lane * 2;
    float v0 = __bfloat162float(hp[0]), v1 = __bfloat162float(hp[1]);
    float pl = ldT(al + lane * 2) * v0 + ldT(al + lane * 2 + 1) * v1;
    float pr = ldT(ar + lane * 2) * v0 + ldT(ar + lane * 2 + 1) * v1;
    for (int off = 8; off; off >>= 1) {   // reduce 16-lane head groups
        pl += __shfl_xor(pl, off);
        pr += __shfl_xor(pr, off);
    }
    if ((lane & 15) == 0) {
        int head = lane >> 4;
        hl[node * 4 + head] = pl;
        hr[node * 4 + head] = pr;
    }
}

__global__ __launch_bounds__(256) void k_count(
    const int* __restrict__ edge, int* __restrict__ counts) {
    int e = blockIdx.x * 256 + threadIdx.x;
    if (e < N_EDGES) atomicAdd(&counts[edge[N_EDGES + e]], 1);
}

__global__ __launch_bounds__(256) void k_scan(
    const int* __restrict__ counts, int* __restrict__ offsets) {
    __shared__ int psum[256];
    int t = threadIdx.x;
    const int CHUNK = 196;
    int start = t * CHUNK;
    int end = min(start + CHUNK, N_NODES);
    int s = 0;
    for (int i = start; i < end; ++i) s += counts[i];
    psum[t] = s;
    __syncthreads();
    for (int off = 1; off < 256; off <<= 1) {
        int v = (t >= off) ? psum[t - off] : 0;
        __syncthreads();
        psum[t] += v;
        __syncthreads();
    }
    int run = (t == 0) ? 0 : psum[t - 1];
    for (int i = start; i < end; ++i) { offsets[i] = run; run += counts[i]; }
    if (t == 255) offsets[N_NODES] = run;
}

__global__ __launch_bounds__(256) void k_scatter_idx(
    const int* __restrict__ edge, const int* __restrict__ offsets,
    int* __restrict__ cursor, int* __restrict__ perm) {
    int e = blockIdx.x * 256 + threadIdx.x;
    if (e >= N_EDGES) return;
    int t = edge[N_EDGES + e];
    int pos = offsets[t] + atomicAdd(&cursor[t], 1);
    perm[pos] = e;
}

__global__ __launch_bounds__(256) void k_scores_max(
    const int* __restrict__ edge,
    const float* __restrict__ hl, const float* __restrict__ hr,
    const float* __restrict__ he, unsigned* __restrict__ gmax) {
    int e = blockIdx.x * 256 + threadIdx.x;
    float m = -3.4e38f;
    if (e < N_EDGES) {
        int s = edge[e], t = edge[N_EDGES + e], ty = edge[2 * N_EDGES + e];
        float4 a = *(const float4*)(hl + s * 4);
        float4 b = *(const float4*)(hr + t * 4);
        float4 c = *(const float4*)(he + ty * 4);
        m = fmaxf(fmaxf(lrelu(a.x + b.x + c.x), lrelu(a.y + b.y + c.y)),
                  fmaxf(lrelu(a.z + b.z + c.z), lrelu(a.w + b.w + c.w)));
    }
    for (int off = 32; off; off >>= 1) m = fmaxf(m, __shfl_xor(m, off));
    __shared__ float wm[4];
    if ((threadIdx.x & 63) == 0) wm[threadIdx.x >> 6] = m;
    __syncthreads();
    if (threadIdx.x == 0) {
        float bm = fmaxf(fmaxf(wm[0], wm[1]), fmaxf(wm[2], wm[3]));
        atomicMax(gmax, enc_f32(bm));
    }
}

// one wave per target node; OUTT = output dtype of the detected world
template<typename OUTT, int EXPECT>
__global__ __launch_bounds__(256) void k_agg(
    const int* __restrict__ edge, const int* __restrict__ perm,
    const int* __restrict__ offsets,
    const float* __restrict__ hl, const float* __restrict__ hr,
    const float* __restrict__ he, const unsigned* __restrict__ gmax,
    const __hip_bfloat16* __restrict__ h,
    void* __restrict__ outv, const int* __restrict__ flag) {
    if (*flag != EXPECT) return;
    OUTT* out = (OUTT*)outv;
    OUTT* attn_out = out + (size_t)N_NODES * 128;
    int node = (blockIdx.x << 2) + (threadIdx.x >> 6);
    if (node >= N_NODES) return;
    int lane = threadIdx.x & 63;
    int beg = offsets[node], end = offsets[node + 1];
    float gm = dec_f32(*gmax);
    float4 b = *(const float4*)(hr + node * 4);

    // pass 1: denom, lanes parallel
    float4 den = {0.f, 0.f, 0.f, 0.f};
    for (int j = beg + lane; j < end; j += 64) {
        int e = perm[j];
        int s = edge[e], ty = edge[2 * N_EDGES + e];
        float4 a = *(const float4*)(hl + s * 4);
        float4 c = *(const float4*)(he + ty * 4);
        den.x += __expf(lrelu(a.x + b.x + c.x) - gm);
        den.y += __expf(lrelu(a.y + b.y + c.y) - gm);
        den.z += __expf(lrelu(a.z + b.z + c.z) - gm);
        den.w += __expf(lrelu(a.w + b.w + c.w) - gm);
    }
    for (int off = 32; off; off >>= 1) {
        den.x += __shfl_xor(den.x, off);
        den.y += __shfl_xor(den.y, off);
        den.z += __shfl_xor(den.z, off);
        den.w += __shfl_xor(den.w, off);
    }
    float inv0 = 1.f / (den.x + 1e-16f), inv1 = 1.f / (den.y + 1e-16f);
    float inv2 = 1.f / (den.z + 1e-16f), inv3 = 1.f / (den.w + 1e-16f);

    // pass 2: serial over this node's edges
    int head = lane >> 4;
    float acc0 = 0.f, acc1 = 0.f;
    for (int j = beg; j < end; ++j) {
        int e = perm[j];
        int s = edge[e], ty = edge[2 * N_EDGES + e];
        float4 a = *(const float4*)(hl + s * 4);
        float4 c = *(const float4*)(he + ty * 4);
        float w0 = __expf(lrelu(a.x + b.x + c.x) - gm) * inv0;
        float w1 = __expf(lrelu(a.y + b.y + c.y) - gm) * inv1;
        float w2 = __expf(lrelu(a.z + b.z + c.z) - gm) * inv2;
        float w3 = __expf(lrelu(a.w + b.w + c.w) - gm) * inv3;
        if (lane < 4) {
            float wv = (lane < 2) ? (lane == 0 ? w0 : w1) : (lane == 2 ? w2 : w3);
            stT(&attn_out[(size_t)e * 4 + lane], wv);
        }
        float wsel = (head < 2) ? (head == 0 ? w0 : w1) : (head == 2 ? w2 : w3);
        const __hip_bfloat16* hp = h + (size_t)s * 128 + lane * 2;
        acc0 += __bfloat162float(hp[0]) * wsel;
        acc1 += __bfloat162float(hp[1]) * wsel;
    }
    stT(&out[(size_t)node * 128 + lane * 2], acc0);
    stT(&out[(size_t)node * 128 + lane * 2 + 1], acc1);
}

extern "C" void kernel_launch(void* const* d_in, const int* in_sizes, int n_in,
                              void* d_out, int out_size, void* d_ws, size_t ws_size,
                              hipStream_t stream) {
    const int* edge = (const int*)d_in[0];
    const void* x   = d_in[1];
    const void* emb = d_in[2];
    const void* W   = d_in[3];
    const void* We  = d_in[4];
    const void* al  = d_in[5];
    const void* ar  = d_in[6];
    const void* ae  = d_in[7];

    float* ws = (float*)d_ws;
    int* counts   = (int*)ws;                       // 50000
    int* cursor   = counts + 50000;                 // 50000
    unsigned* gmx = (unsigned*)(counts + 100000);   // 1
    int* flag     = counts + 100001;                // 1
    int* offsets  = counts + 100064;                // 50001 -> pad 150080
    float* hl     = ws + 150080;                    // 200000
    float* hr     = ws + 350080;                    // 200000
    float* he     = ws + 550080;                    // 32 -> 550112
    int* perm     = (int*)ws + 550112;              // 1600000 -> 2150112
    __hip_bfloat16* h = (__hip_bfloat16*)(ws + 2150112); // 6.4M bf16
    // total 5,350,112 words = 21.4 MB

    hipMemsetAsync(ws, 0, (size_t)100064 * 4, stream);   // counts+cursor+gmax

    k_detect<<<1, 64, 0, stream>>>((const unsigned*)x, flag);

    k_node_proj_s<float, 1><<<12500, 256, 0, stream>>>(x, W, h, flag);
    k_node_proj_s<__hip_bfloat16, 0><<<12500, 256, 0, stream>>>(x, W, h, flag);

    k_edge_proj<float, 1><<<1, 256, 0, stream>>>(emb, We, ae, he, flag);
    k_edge_proj<__hip_bfloat16, 0><<<1, 256, 0, stream>>>(emb, We, ae, he, flag);

    k_hlr<float, 1><<<12500, 256, 0, stream>>>(h, al, ar, hl, hr, flag);
    k_hlr<__hip_bfloat16, 0><<<12500, 256, 0, stream>>>(h, al, ar, hl, hr, flag);

    k_count<<<6250, 256, 0, stream>>>(edge, counts);
    k_scan<<<1, 256, 0, stream>>>(counts, offsets);
    k_scatter_idx<<<6250, 256, 0, stream>>>(edge, offsets, cursor, perm);
    k_scores_max<<<6250, 256, 0, stream>>>(edge, hl, hr, he, gmx);

    k_agg<float, 1><<<12500, 256, 0, stream>>>(edge, perm, offsets, hl, hr, he,
                                               gmx, h, d_out, flag);
    k_agg<__hip_bfloat16, 0><<<12500, 256, 0, stream>>>(edge, perm, offsets, hl,
                                                        hr, he, gmx, h, d_out, flag);
}